// Round 1
// baseline (1305.688 us; speedup 1.0000x reference)
//
#include <hip/hip_runtime.h>
#include <hip/hip_bf16.h>

// Stable partition-by-species of two feature arrays.
//   feat_a [N,128] f32, feat_b [N,64] f32, species [N] i32 (values 0..3)
// Output: feat_a rows in stable-sorted-by-species order (N*128 floats),
// then feat_b rows likewise (N*64 floats).
//
// Plan: per-chunk histograms -> exclusive scan -> rank + float4 row scatter.

#define CHUNK 256          // atoms per block (block = 256 threads)
#define NSPEC 4

// ---------------------------------------------------------------- kernel 1
__global__ __launch_bounds__(256) void cs_hist(const int* __restrict__ species,
                                               int* __restrict__ counts,
                                               int num_chunks) {
    const int chunk = blockIdx.x;
    const int tid   = threadIdx.x;
    const int s     = species[chunk * CHUNK + tid];

    const int lane = tid & 63;
    const int wave = tid >> 6;
    __shared__ int wcnt[4][NSPEC];   // [wave][species]

    unsigned long long m0 = __ballot(s == 0);
    unsigned long long m1 = __ballot(s == 1);
    unsigned long long m2 = __ballot(s == 2);
    unsigned long long m3 = __ballot(s == 3);
    if (lane == 0) {
        wcnt[wave][0] = __popcll(m0);
        wcnt[wave][1] = __popcll(m1);
        wcnt[wave][2] = __popcll(m2);
        wcnt[wave][3] = __popcll(m3);
    }
    __syncthreads();
    if (tid < NSPEC) {
        counts[chunk * NSPEC + tid] =
            wcnt[0][tid] + wcnt[1][tid] + wcnt[2][tid] + wcnt[3][tid];
    }
}

// ---------------------------------------------------------------- kernel 2
// Single block, 1024 threads. Converts counts[chunk][s] into the global
// starting row offset for (chunk, s): species_base + exclusive prefix over
// all earlier chunks for that species.
__global__ __launch_bounds__(1024) void cs_scan(int* __restrict__ counts,
                                                int num_chunks) {
    const int T   = 1024;
    const int tid = threadIdx.x;
    const int cpt = (num_chunks + T - 1) / T;   // chunks per thread

    __shared__ int sdata[1024];
    __shared__ int stotal[NSPEC];
    __shared__ int sbase[NSPEC];

    int excl[NSPEC];

    for (int s = 0; s < NSPEC; ++s) {
        int sum = 0;
        for (int k = 0; k < cpt; ++k) {
            int c = tid * cpt + k;
            if (c < num_chunks) sum += counts[c * NSPEC + s];
        }
        sdata[tid] = sum;
        __syncthreads();
        // Hillis-Steele inclusive scan over 1024 threads
        for (int off = 1; off < T; off <<= 1) {
            int v = (tid >= off) ? sdata[tid - off] : 0;
            __syncthreads();
            sdata[tid] += v;
            __syncthreads();
        }
        int incl = sdata[tid];
        excl[s] = incl - sum;
        if (tid == T - 1) stotal[s] = incl;
        __syncthreads();
    }

    if (tid == 0) {
        int b = 0;
        for (int s = 0; s < NSPEC; ++s) { sbase[s] = b; b += stotal[s]; }
    }
    __syncthreads();

    for (int s = 0; s < NSPEC; ++s) {
        int run = sbase[s] + excl[s];
        for (int k = 0; k < cpt; ++k) {
            int c = tid * cpt + k;
            if (c < num_chunks) {
                int cnt = counts[c * NSPEC + s];
                counts[c * NSPEC + s] = run;
                run += cnt;
            }
        }
    }
}

// ---------------------------------------------------------------- kernel 3
// offs[chunk][s] = global starting row for that (chunk, species).
// dest row for atom i = offs[chunk][s_i] + stable local rank of i among
// same-species atoms in the chunk.
__global__ __launch_bounds__(256) void cs_scatter(const float4* __restrict__ fa,
                                                  const float4* __restrict__ fb,
                                                  const int* __restrict__ species,
                                                  const int* __restrict__ offs,
                                                  float4* __restrict__ out,
                                                  int n) {
    const int chunk = blockIdx.x;
    const int tid   = threadIdx.x;
    const int atom  = chunk * CHUNK + tid;
    const int s     = species[atom];

    const int lane = tid & 63;
    const int wave = tid >> 6;

    __shared__ int wcnt[4][NSPEC];   // per-wave per-species counts
    __shared__ int dest[CHUNK];      // destination row per atom

    unsigned long long m0 = __ballot(s == 0);
    unsigned long long m1 = __ballot(s == 1);
    unsigned long long m2 = __ballot(s == 2);
    unsigned long long m3 = __ballot(s == 3);
    if (lane == 0) {
        wcnt[wave][0] = __popcll(m0);
        wcnt[wave][1] = __popcll(m1);
        wcnt[wave][2] = __popcll(m2);
        wcnt[wave][3] = __popcll(m3);
    }
    __syncthreads();

    unsigned long long ms = (s == 0) ? m0 : (s == 1) ? m1 : (s == 2) ? m2 : m3;
    unsigned long long lanemask = (lane == 0) ? 0ull : ((1ull << lane) - 1ull);
    int rank = __popcll(ms & lanemask);
    for (int w = 0; w < wave; ++w) rank += wcnt[w][s];

    dest[tid] = offs[chunk * NSPEC + s] + rank;
    __syncthreads();

    // ---- copy feat_a rows: 128 f32 = 32 float4 per row ----
    const float4* srcA = fa + (size_t)chunk * CHUNK * 32;
    #pragma unroll
    for (int i = tid; i < CHUNK * 32; i += 256) {
        int a = i >> 5, c = i & 31;
        out[(size_t)dest[a] * 32 + c] = srcA[i];
    }

    // ---- copy feat_b rows: 64 f32 = 16 float4 per row ----
    const float4* srcB = fb + (size_t)chunk * CHUNK * 16;
    float4* outB = out + (size_t)n * 32;   // after N*128 floats of out_a
    #pragma unroll
    for (int i = tid; i < CHUNK * 16; i += 256) {
        int a = i >> 4, c = i & 15;
        outB[(size_t)dest[a] * 16 + c] = srcB[i];
    }
}

// ---------------------------------------------------------------- launch
extern "C" void kernel_launch(void* const* d_in, const int* in_sizes, int n_in,
                              void* d_out, int out_size, void* d_ws, size_t ws_size,
                              hipStream_t stream) {
    const float* feat_a  = (const float*)d_in[0];
    const float* feat_b  = (const float*)d_in[1];
    const int*   species = (const int*)d_in[2];
    float*       out     = (float*)d_out;

    const int n = in_sizes[2];            // 1048576, divisible by CHUNK
    const int num_chunks = n / CHUNK;     // 4096

    int* counts = (int*)d_ws;             // num_chunks * 4 ints = 64 KB

    cs_hist<<<num_chunks, 256, 0, stream>>>(species, counts, num_chunks);
    cs_scan<<<1, 1024, 0, stream>>>(counts, num_chunks);
    cs_scatter<<<num_chunks, 256, 0, stream>>>((const float4*)feat_a,
                                               (const float4*)feat_b,
                                               species, counts,
                                               (float4*)out, n);
}